// Round 9
// baseline (311.912 us; speedup 1.0000x reference)
//
#include <hip/hip_runtime.h>
#include <hip/hip_bf16.h>
#include <math.h>

// Problem constants (fixed by setup_inputs: B=4, L=2048)
#define BB      4
#define LL      2048
#define KNB     30
#define NRES    (BB*LL)          // 8192
#define NEDGE   (NRES*KNB)       // 245760
#define EDGE_IN 416              // 16 pos + 25*16 RBF = 13 * 32
#define KT      13               // K-tiles of 32
#define ME      64               // edges per block in edge kernel
#define AST3    168              // A-tile row stride in fp16 for 5-tile buffer (336 B, 16B-aligned)
#define FINF    3.4e38f
#define LOG2E   1.44269504088896340736f

typedef __attribute__((ext_vector_type(8))) _Float16 half8;
typedef __attribute__((ext_vector_type(4))) float floatx4;

__device__ __constant__ int d_PA[25] = {0,1,2,3,4,0,0,0,0,1,1,1,4,4,3,1,2,3,4,2,3,4,2,3,2};
__device__ __constant__ int d_PB[25] = {0,1,2,3,4,1,2,3,4,2,3,4,2,3,2,0,0,0,0,1,1,1,4,4,3};

__device__ __forceinline__ unsigned short f2h_bits(float x) {
    _Float16 h = (_Float16)x;
    union { _Float16 h; unsigned short u; } v; v.h = h;
    return v.u;
}
__device__ __forceinline__ unsigned pack2h(float a, float b) {
    return (unsigned)f2h_bits(a) | ((unsigned)f2h_bits(b) << 16);
}

// ---------------------------------------------------------------------------
// Kernel 1: per-residue atom construction.  atoms[r][5][3] = [Ca,N,C,O,Cb].
// Also emits the Ca SoA transpose (caTx/y/z) for coalesced topk loads.
// ---------------------------------------------------------------------------
__global__ __launch_bounds__(256) void atoms_kernel(const float* __restrict__ X,
                                                    float* __restrict__ atoms,
                                                    float* __restrict__ caTx,
                                                    float* __restrict__ caTy,
                                                    float* __restrict__ caTz) {
    int r = blockIdx.x * blockDim.x + threadIdx.x;
    if (r >= NRES) return;
    const float* xr = X + (size_t)r * 12;
    float Nx = xr[0],  Ny = xr[1],  Nz = xr[2];
    float Ax = xr[3],  Ay = xr[4],  Az = xr[5];   // Ca
    float Cx = xr[6],  Cy = xr[7],  Cz = xr[8];
    float Ox = xr[9],  Oy = xr[10], Oz = xr[11];
    float bx = Ax - Nx, by = Ay - Ny, bz = Az - Nz;
    float cx = Cx - Ax, cy = Cy - Ay, cz = Cz - Az;
    float ax = by * cz - bz * cy;
    float ay = bz * cx - bx * cz;
    float az = bx * cy - by * cx;
    float Cbx = -0.58273431f * ax + 0.56802827f * bx - 0.54067466f * cx + Ax;
    float Cby = -0.58273431f * ay + 0.56802827f * by - 0.54067466f * cy + Ay;
    float Cbz = -0.58273431f * az + 0.56802827f * bz - 0.54067466f * cz + Az;
    float* o = atoms + (size_t)r * 15;
    o[0]  = Ax;  o[1]  = Ay;  o[2]  = Az;
    o[3]  = Nx;  o[4]  = Ny;  o[5]  = Nz;
    o[6]  = Cx;  o[7]  = Cy;  o[8]  = Cz;
    o[9]  = Ox;  o[10] = Oy;  o[11] = Oz;
    o[12] = Cbx; o[13] = Cby; o[14] = Cbz;
    caTx[r] = Ax; caTy[r] = Ay; caTz[r] = Az;     // exact copies of X values
}

// ---------------------------------------------------------------------------
// Kernel 2: top-K — TWO RESIDUES PER WAVE, cached-head tournament, ZERO LDS.
// The per-round 6-step shuffle butterfly is a serial LDS-pipe latency chain
// (~60 cyc/step); two independent chains per wave interleave at issue time,
// hiding each other's latency.  Neighbor coords/mask are loaded ONCE and used
// for both centers.  Per-residue arithmetic, op order and selection rule are
// byte-identical to the 1-residue version => E_idx bit-identical.
// (launch_bounds min-waves clamp removed to avoid forced-spill risk.)
// ---------------------------------------------------------------------------
__global__ __launch_bounds__(256) void topk_kernel(const float* __restrict__ caTx,
                                                   const float* __restrict__ caTy,
                                                   const float* __restrict__ caTz,
                                                   const float* __restrict__ mask,
                                                   int* __restrict__ E_idx) {
#pragma clang fp contract(off)
    int t    = threadIdx.x;
    int wid  = t >> 6;
    int lane = t & 63;
    int bi0  = blockIdx.x * 8 + wid * 2;      // two adjacent residues
    int bi1  = bi0 + 1;
    int b    = bi0 >> 11;                      // same batch for both (8-aligned)
    int j0   = b << 11;

    float cx0 = caTx[bi0], cy0 = caTy[bi0], cz0 = caTz[bi0];
    float cx1 = caTx[bi1], cy1 = caTy[bi1], cz1 = caTz[bi1];
    float mi0 = mask[bi0], mi1 = mask[bi1];

    float a0[32], a1[32];
    float lmax0 = 0.0f, lmax1 = 0.0f;
#pragma unroll
    for (int i = 0; i < 32; i++) {
        int j = j0 + i * 64 + lane;
        float px = caTx[j], py = caTy[j], pz = caTz[j];
        float mj = mask[j];
        float dx0 = cx0 - px, dy0 = cy0 - py, dz0 = cz0 - pz;
        float dx1 = cx1 - px, dy1 = cy1 - py, dz1 = cz1 - pz;
        float ssq0 = ((dx0 * dx0 + dy0 * dy0) + dz0 * dz0) + 1e-6f;
        float ssq1 = ((dx1 * dx1 + dy1 * dy1) + dz1 * dz1) + 1e-6f;
        float m20 = mj * mi0;
        float m21 = mj * mi1;
        float D0 = m20 * sqrtf(ssq0);
        float D1 = m21 * sqrtf(ssq1);
        a0[i] = D0; a1[i] = D1;
        lmax0 = fmaxf(lmax0, D0);
        lmax1 = fmaxf(lmax1, D1);
    }
    for (int off = 32; off; off >>= 1) {
        lmax0 = fmaxf(lmax0, __shfl_xor(lmax0, off));
        lmax1 = fmaxf(lmax1, __shfl_xor(lmax1, off));
    }

    // adjust in place (exact no-op when mask==1) and build sorted-4 caches
    float p0 = FINF, p1 = FINF, p2 = FINF, p3 = FINF;   // residue 0 heads
    int   q0 = 0,    q1 = 0,    q2 = 0,    q3 = 0;
    float r0 = FINF, r1 = FINF, r2 = FINF, r3 = FINF;   // residue 1 heads
    int   s0 = 0,    s1 = 0,    s2 = 0,    s3 = 0;
#pragma unroll
    for (int i = 0; i < 32; i++) {
        float mj = mask[j0 + i * 64 + lane];
        float v0 = a0[i] + (1.0f - mj * mi0) * lmax0;
        float v1 = a1[i] + (1.0f - mj * mi1) * lmax1;
        a0[i] = v0; a1[i] = v1;
        {
            bool c0 = v0 < p0, c1 = v0 < p1, c2 = v0 < p2, c3 = v0 < p3;
            p3 = c2 ? p2 : (c3 ? v0 : p3);  q3 = c2 ? q2 : (c3 ? i : q3);
            p2 = c1 ? p1 : (c2 ? v0 : p2);  q2 = c1 ? q1 : (c2 ? i : q2);
            p1 = c0 ? p0 : (c1 ? v0 : p1);  q1 = c0 ? q0 : (c1 ? i : q1);
            p0 = c0 ? v0 : p0;              q0 = c0 ? i  : q0;
        }
        {
            bool c0 = v1 < r0, c1 = v1 < r1, c2 = v1 < r2, c3 = v1 < r3;
            r3 = c2 ? r2 : (c3 ? v1 : r3);  s3 = c2 ? s2 : (c3 ? i : s3);
            r2 = c1 ? r1 : (c2 ? v1 : r2);  s2 = c1 ? s1 : (c2 ? i : s2);
            r1 = c0 ? r0 : (c1 ? v1 : r1);  s1 = c0 ? s0 : (c1 ? i : s1);
            r0 = c0 ? v1 : r0;              s0 = c0 ? i  : s0;
        }
    }

    unsigned cons0 = 0, cons1 = 0;
    int* outp0 = E_idx + (size_t)bi0 * KNB;
    int* outp1 = E_idx + (size_t)bi1 * KNB;
#pragma unroll 1
    for (int r = 0; r < KNB; r++) {
        // --- two independent 6-step lexicographic butterflies, interleaved ---
        float bv0 = p0, bv1 = r0;
        int   bj0 = (q0 << 6) | lane;
        int   bj1 = (s0 << 6) | lane;
        for (int off = 1; off < 64; off <<= 1) {
            float ov0 = __shfl_xor(bv0, off);
            float ov1 = __shfl_xor(bv1, off);
            int   oj0 = __shfl_xor(bj0, off);
            int   oj1 = __shfl_xor(bj1, off);
            if (ov0 < bv0 || (ov0 == bv0 && oj0 < bj0)) { bv0 = ov0; bj0 = oj0; }
            if (ov1 < bv1 || (ov1 == bv1 && oj1 < bj1)) { bv1 = ov1; bj1 = oj1; }
        }
        if (lane == 0) { outp0[r] = bj0; outp1[r] = bj1; }
        // --- pop winners ---
        bool mine0 = ((bj0 & 63) == lane);
        if (mine0) {
            cons0 |= 1u << ((unsigned)bj0 >> 6);
            p0 = p1; q0 = q1;
            p1 = p2; q1 = q2;
            p2 = p3; q2 = q3;
            p3 = FINF;
        }
        bool mine1 = ((bj1 & 63) == lane);
        if (mine1) {
            cons1 |= 1u << ((unsigned)bj1 >> 6);
            r0 = r1; s0 = s1;
            r1 = r2; s1 = s2;
            r2 = r3; s2 = s3;
            r3 = FINF;
        }
        // --- rare refills (lane won a 5th time) ---
        if (mine0 && (p0 == FINF) && (r < KNB - 1)) {
            p0 = FINF; p1 = FINF; p2 = FINF; p3 = FINF;
            q0 = 0; q1 = 0; q2 = 0; q3 = 0;
#pragma unroll
            for (int i = 0; i < 32; i++) {
                float v = (cons0 & (1u << i)) ? FINF : a0[i];
                bool c0 = v < p0, c1 = v < p1, c2 = v < p2, c3 = v < p3;
                p3 = c2 ? p2 : (c3 ? v : p3);  q3 = c2 ? q2 : (c3 ? i : q3);
                p2 = c1 ? p1 : (c2 ? v : p2);  q2 = c1 ? q1 : (c2 ? i : q2);
                p1 = c0 ? p0 : (c1 ? v : p1);  q1 = c0 ? q0 : (c1 ? i : q1);
                p0 = c0 ? v  : p0;             q0 = c0 ? i  : q0;
            }
        }
        if (mine1 && (r0 == FINF) && (r < KNB - 1)) {
            r0 = FINF; r1 = FINF; r2 = FINF; r3 = FINF;
            s0 = 0; s1 = 0; s2 = 0; s3 = 0;
#pragma unroll
            for (int i = 0; i < 32; i++) {
                float v = (cons1 & (1u << i)) ? FINF : a1[i];
                bool c0 = v < r0, c1 = v < r1, c2 = v < r2, c3 = v < r3;
                r3 = c2 ? r2 : (c3 ? v : r3);  s3 = c2 ? s2 : (c3 ? i : s3);
                r2 = c1 ? r1 : (c2 ? v : r2);  s2 = c1 ? s1 : (c2 ? i : s2);
                r1 = c0 ? r0 : (c1 ? v : r1);  s1 = c0 ? s0 : (c1 ? i : s1);
                r0 = c0 ? v  : r0;             s0 = c0 ? i  : s0;
            }
        }
    }
}

// ---------------------------------------------------------------------------
// Kernel 2.5: pre-swizzle W_edge (fp32 [416][128]) into SPLIT fp16 B-fragment
// order: Wh = fp16(W), Wl = fp16(W - Wh).  Layout [kk][nt][lane] of half8:
// element holds W[k = kk*32 + (lane>>4)*8 + j][n = nt*16 + (lane&15)].
// ---------------------------------------------------------------------------
__global__ __launch_bounds__(256) void wprep_kernel(const float* __restrict__ W_edge,
                                                    half8* __restrict__ Wfh,
                                                    half8* __restrict__ Wfl) {
    int t = blockIdx.x * blockDim.x + threadIdx.x;
    if (t >= KT * 8 * 64) return;
    int kk   = t >> 9;
    int rem  = t & 511;
    int nt   = rem >> 6;
    int lane = rem & 63;
    int n  = nt * 16 + (lane & 15);
    int kb = kk * 32 + (lane >> 4) * 8;
    half8 vh, vl;
#pragma unroll
    for (int j = 0; j < 8; j++) {
        float w = W_edge[(size_t)(kb + j) * 128 + n];
        _Float16 wh = (_Float16)w;
        vh[j] = wh;
        vl[j] = (_Float16)(w - (float)wh);
    }
    Wfh[t] = vh;
    Wfl[t] = vl;
}

// ---------------------------------------------------------------------------
// Kernel 3: edge featurization (SPLIT fp16 A-tile) + 3-term MFMA GEMM + LN.
// (byte-identical to round 6: ME=64, acc[2][4], 3-way K time-split)
// ---------------------------------------------------------------------------
__global__ __launch_bounds__(256) void edge_kernel(const float* __restrict__ atoms,
                                                   const int* __restrict__ E_idx,
                                                   const int* __restrict__ resi,
                                                   const float* __restrict__ W_pos,
                                                   const float* __restrict__ b_pos,
                                                   const half8* __restrict__ Wfh,
                                                   const half8* __restrict__ Wfl,
                                                   const float* __restrict__ gamma,
                                                   const float* __restrict__ beta,
                                                   float* __restrict__ out) {
    __shared__ _Float16 Ah[ME * AST3];             // 21504 B
    __shared__ _Float16 Al[ME * AST3];             // 21504 B
    __shared__ float Dl[ME][26];                   //  6656 B
    __shared__ float redS[2][ME];                  //   512 B
    __shared__ int   s_gi[ME], s_gj[ME], s_d[ME];  //   768 B

    int t  = threadIdx.x;
    int e0 = blockIdx.x * ME;

    if (t < ME) {
        int e  = e0 + t;
        int gi = e / KNB;
        int k  = e - gi * KNB;
        int b  = gi >> 11;
        int j  = E_idx[(size_t)gi * KNB + k];
        s_gi[t] = gi;
        s_gj[t] = (b << 11) + j;
        int off = resi[gi] - resi[(b << 11) + j];
        int d = off + 32;
        s_d[t] = d < 0 ? 0 : (d > 64 ? 64 : d);
    }
    __syncthreads();

    for (int idx = t; idx < ME * 25; idx += 256) {
        int e = idx / 25, p = idx - e * 25;
        const float* Ar = atoms + (size_t)s_gi[e] * 15 + d_PA[p] * 3;
        const float* Br = atoms + (size_t)s_gj[e] * 15 + d_PB[p] * 3;
        float dx = Ar[0] - Br[0];
        float dy = Ar[1] - Br[1];
        float dz = Ar[2] - Br[2];
        Dl[e][p] = sqrtf(dx * dx + dy * dy + dz * dz + 1e-6f);
    }
    __syncthreads();

    int fe  = t >> 2;           // 0..63 (edge for fill)
    int fj4 = t & 3;
    const float* dle = Dl[fe];
    _Float16* fah = &Ah[fe * AST3];
    _Float16* fal = &Al[fe * AST3];

    // --- fill pass 0: features 0..159 (pos-emb + RBF pairs i=0..17) ---
    {
        {                          // pos-emb features c = fj4*4 .. +3
            int c = fj4 * 4;
            int dpos = s_d[fe];
            const float* wp = W_pos + dpos * 16 + c;
            float v[4];
#pragma unroll
            for (int q = 0; q < 4; q++) v[q] = wp[q] + b_pos[c + q];
            float h0 = (float)(_Float16)v[0], h1 = (float)(_Float16)v[1];
            float h2 = (float)(_Float16)v[2], h3 = (float)(_Float16)v[3];
            *(unsigned*)&fah[c + 0] = pack2h(v[0], v[1]);
            *(unsigned*)&fah[c + 2] = pack2h(v[2], v[3]);
            *(unsigned*)&fal[c + 0] = pack2h(v[0] - h0, v[1] - h1);
            *(unsigned*)&fal[c + 2] = pack2h(v[2] - h2, v[3] - h3);
        }
        // RBF pairs: c2 = 2*(fj4 + 4i), i = 0..17 -> buffer col 16+c2 (<=158)
#pragma unroll
        for (int i = 0; i < 18; i++) {
            int c2 = 2 * (fj4 + 4 * i);
            int p  = c2 >> 4;
            int r  = c2 & 15;
            float D = dle[p];
            float mu0 = 2.0f + (float)r * (20.0f / 15.0f);
            float mu1 = 2.0f + (float)(r + 1) * (20.0f / 15.0f);
            float t0 = (D - mu0) * 0.8f;
            float t1 = (D - mu1) * 0.8f;
            float g0 = __builtin_amdgcn_exp2f(-(t0 * t0) * LOG2E);
            float g1 = __builtin_amdgcn_exp2f(-(t1 * t1) * LOG2E);
            float h0 = (float)(_Float16)g0, h1 = (float)(_Float16)g1;
            *(unsigned*)&fah[16 + c2] = pack2h(g0, g1);
            *(unsigned*)&fal[16 + c2] = pack2h(g0 - h0, g1 - h1);
        }
    }
    __syncthreads();

    // --- MFMA GEMM: 64x416 x 416x128 -> fp32, split precision, 3-way K split ---
    int lane  = t & 63;
    int w     = t >> 6;
    int ms    = w & 1;             // edge strip pair: rows ms*32 .. ms*32+31
    int h     = w >> 1;            // feature half (0: n 0..63, 1: n 64..127)
    int m     = lane & 15;
    int quad  = lane >> 4;
    const _Float16* pah = &Ah[(ms * 32 + m) * AST3 + quad * 8];
    const _Float16* pal = &Al[(ms * 32 + m) * AST3 + quad * 8];

    floatx4 acc[2][4];
#pragma unroll
    for (int s = 0; s < 2; s++)
#pragma unroll
        for (int c = 0; c < 4; c++) acc[s][c] = (floatx4){0.f, 0.f, 0.f, 0.f};

    half8 bh[4], bl[4], bnh[4], bnl[4];
#pragma unroll
    for (int c = 0; c < 4; c++) {
        int idx = (h * 4 + c) * 64 + lane;
        bh[c] = Wfh[idx];
        bl[c] = Wfl[idx];
    }

    // pass 0: k-tiles 0..4 (prefetch kk+1 <= 5 always valid)
#pragma unroll 1
    for (int kk = 0; kk < 5; kk++) {
        half8 a_hi0 = *(const half8*)(pah + kk * 32);
        half8 a_lo0 = *(const half8*)(pal + kk * 32);
        half8 a_hi1 = *(const half8*)(pah + 16 * AST3 + kk * 32);
        half8 a_lo1 = *(const half8*)(pal + 16 * AST3 + kk * 32);
#pragma unroll
        for (int c = 0; c < 4; c++) {
            int idx = ((kk + 1) * 8 + h * 4 + c) * 64 + lane;
            bnh[c] = Wfh[idx];
            bnl[c] = Wfl[idx];
        }
#pragma unroll
        for (int c = 0; c < 4; c++) {
            acc[0][c] = __builtin_amdgcn_mfma_f32_16x16x32_f16(a_hi0, bh[c], acc[0][c], 0, 0, 0);
            acc[1][c] = __builtin_amdgcn_mfma_f32_16x16x32_f16(a_hi1, bh[c], acc[1][c], 0, 0, 0);
            acc[0][c] = __builtin_amdgcn_mfma_f32_16x16x32_f16(a_lo0, bh[c], acc[0][c], 0, 0, 0);
            acc[1][c] = __builtin_amdgcn_mfma_f32_16x16x32_f16(a_lo1, bh[c], acc[1][c], 0, 0, 0);
            acc[0][c] = __builtin_amdgcn_mfma_f32_16x16x32_f16(a_hi0, bl[c], acc[0][c], 0, 0, 0);
            acc[1][c] = __builtin_amdgcn_mfma_f32_16x16x32_f16(a_hi1, bl[c], acc[1][c], 0, 0, 0);
        }
#pragma unroll
        for (int c = 0; c < 4; c++) { bh[c] = bnh[c]; bl[c] = bnl[c]; }
    }

    __syncthreads();   // all waves done reading buffer

    // --- fill pass 1: features 160..287 (RBF pairs i=18..33), col = c2-144 ---
    {
#pragma unroll
        for (int i = 18; i < 34; i++) {
            int c2 = 2 * (fj4 + 4 * i);
            int p  = c2 >> 4;
            int r  = c2 & 15;
            float D = dle[p];
            float mu0 = 2.0f + (float)r * (20.0f / 15.0f);
            float mu1 = 2.0f + (float)(r + 1) * (20.0f / 15.0f);
            float t0 = (D - mu0) * 0.8f;
            float t1 = (D - mu1) * 0.8f;
            float g0 = __builtin_amdgcn_exp2f(-(t0 * t0) * LOG2E);
            float g1 = __builtin_amdgcn_exp2f(-(t1 * t1) * LOG2E);
            float h0 = (float)(_Float16)g0, h1 = (float)(_Float16)g1;
            int col = c2 - 144;
            *(unsigned*)&fah[col] = pack2h(g0, g1);
            *(unsigned*)&fal[col] = pack2h(g0 - h0, g1 - h1);
        }
    }
    __syncthreads();

    // pass 1: k-tiles 5..8 (prefetch kk+1 <= 9 always valid)
#pragma unroll 1
    for (int kk = 5; kk < 9; kk++) {
        half8 a_hi0 = *(const half8*)(pah + (kk - 5) * 32);
        half8 a_lo0 = *(const half8*)(pal + (kk - 5) * 32);
        half8 a_hi1 = *(const half8*)(pah + 16 * AST3 + (kk - 5) * 32);
        half8 a_lo1 = *(const half8*)(pal + 16 * AST3 + (kk - 5) * 32);
#pragma unroll
        for (int c = 0; c < 4; c++) {
            int idx = ((kk + 1) * 8 + h * 4 + c) * 64 + lane;
            bnh[c] = Wfh[idx];
            bnl[c] = Wfl[idx];
        }
#pragma unroll
        for (int c = 0; c < 4; c++) {
            acc[0][c] = __builtin_amdgcn_mfma_f32_16x16x32_f16(a_hi0, bh[c], acc[0][c], 0, 0, 0);
            acc[1][c] = __builtin_amdgcn_mfma_f32_16x16x32_f16(a_hi1, bh[c], acc[1][c], 0, 0, 0);
            acc[0][c] = __builtin_amdgcn_mfma_f32_16x16x32_f16(a_lo0, bh[c], acc[0][c], 0, 0, 0);
            acc[1][c] = __builtin_amdgcn_mfma_f32_16x16x32_f16(a_lo1, bh[c], acc[1][c], 0, 0, 0);
            acc[0][c] = __builtin_amdgcn_mfma_f32_16x16x32_f16(a_hi0, bl[c], acc[0][c], 0, 0, 0);
            acc[1][c] = __builtin_amdgcn_mfma_f32_16x16x32_f16(a_hi1, bl[c], acc[1][c], 0, 0, 0);
        }
#pragma unroll
        for (int c = 0; c < 4; c++) { bh[c] = bnh[c]; bl[c] = bnl[c]; }
    }

    __syncthreads();   // all waves done reading buffer

    // --- fill pass 2: features 288..415 (RBF pairs i=34..49), col = c2-272 ---
    {
#pragma unroll
        for (int i = 34; i < 50; i++) {
            int c2 = 2 * (fj4 + 4 * i);
            int p  = c2 >> 4;
            int r  = c2 & 15;
            float D = dle[p];
            float mu0 = 2.0f + (float)r * (20.0f / 15.0f);
            float mu1 = 2.0f + (float)(r + 1) * (20.0f / 15.0f);
            float t0 = (D - mu0) * 0.8f;
            float t1 = (D - mu1) * 0.8f;
            float g0 = __builtin_amdgcn_exp2f(-(t0 * t0) * LOG2E);
            float g1 = __builtin_amdgcn_exp2f(-(t1 * t1) * LOG2E);
            float h0 = (float)(_Float16)g0, h1 = (float)(_Float16)g1;
            int col = c2 - 272;
            *(unsigned*)&fah[col] = pack2h(g0, g1);
            *(unsigned*)&fal[col] = pack2h(g0 - h0, g1 - h1);
        }
    }
    __syncthreads();

    // pass 2: k-tiles 9..12 (guard prefetch at kk==12)
#pragma unroll 1
    for (int kk = 9; kk < KT; kk++) {
        half8 a_hi0 = *(const half8*)(pah + (kk - 9) * 32);
        half8 a_lo0 = *(const half8*)(pal + (kk - 9) * 32);
        half8 a_hi1 = *(const half8*)(pah + 16 * AST3 + (kk - 9) * 32);
        half8 a_lo1 = *(const half8*)(pal + 16 * AST3 + (kk - 9) * 32);
        if (kk < KT - 1) {
#pragma unroll
            for (int c = 0; c < 4; c++) {
                int idx = ((kk + 1) * 8 + h * 4 + c) * 64 + lane;
                bnh[c] = Wfh[idx];
                bnl[c] = Wfl[idx];
            }
        }
#pragma unroll
        for (int c = 0; c < 4; c++) {
            acc[0][c] = __builtin_amdgcn_mfma_f32_16x16x32_f16(a_hi0, bh[c], acc[0][c], 0, 0, 0);
            acc[1][c] = __builtin_amdgcn_mfma_f32_16x16x32_f16(a_hi1, bh[c], acc[1][c], 0, 0, 0);
            acc[0][c] = __builtin_amdgcn_mfma_f32_16x16x32_f16(a_lo0, bh[c], acc[0][c], 0, 0, 0);
            acc[1][c] = __builtin_amdgcn_mfma_f32_16x16x32_f16(a_lo1, bh[c], acc[1][c], 0, 0, 0);
            acc[0][c] = __builtin_amdgcn_mfma_f32_16x16x32_f16(a_hi0, bl[c], acc[0][c], 0, 0, 0);
            acc[1][c] = __builtin_amdgcn_mfma_f32_16x16x32_f16(a_hi1, bl[c], acc[1][c], 0, 0, 0);
        }
#pragma unroll
        for (int c = 0; c < 4; c++) { bh[c] = bnh[c]; bl[c] = bnl[c]; }
    }

    // --- LayerNorm epilogue: per edge, features split across wave pairs ---
    // D[row = quad*4 + r][col = m] per strip; edge_local = ms*32 + s*16 + quad*4 + r.
#pragma unroll
    for (int s = 0; s < 2; s++) {
        int elb = ms * 32 + s * 16 + quad * 4;
        float sarr[4];
#pragma unroll
        for (int r = 0; r < 4; r++) {
            float sm = acc[s][0][r] + acc[s][1][r] + acc[s][2][r] + acc[s][3][r];
            for (int msk = 1; msk <= 8; msk <<= 1) sm += __shfl_xor(sm, msk);
            sarr[r] = sm;
        }
        if (m == 0) {
#pragma unroll
            for (int r = 0; r < 4; r++) redS[h][elb + r] = sarr[r];
        }
        __syncthreads();
        float mu[4];
#pragma unroll
        for (int r = 0; r < 4; r++) mu[r] = (redS[0][elb + r] + redS[1][elb + r]) * (1.0f / 128.0f);
        __syncthreads();
        float dvv[4][4];
#pragma unroll
        for (int r = 0; r < 4; r++) {
            float v = 0.f;
#pragma unroll
            for (int c = 0; c < 4; c++) { dvv[c][r] = acc[s][c][r] - mu[r]; v += dvv[c][r] * dvv[c][r]; }
            for (int msk = 1; msk <= 8; msk <<= 1) v += __shfl_xor(v, msk);
            if (m == 0) redS[h][elb + r] = v;
        }
        __syncthreads();
#pragma unroll
        for (int r = 0; r < 4; r++) {
            float var  = (redS[0][elb + r] + redS[1][elb + r]) * (1.0f / 128.0f);
            float rstd = rsqrtf(var + 1e-5f);
            int e = e0 + elb + r;
            float* orow = out + (size_t)e * 128;
#pragma unroll
            for (int c = 0; c < 4; c++) {
                int n = (h * 4 + c) * 16 + m;
                orow[n] = dvv[c][r] * rstd * gamma[n] + beta[n];
            }
        }
        if (s == 0) __syncthreads();   // redS reused by strip 1
    }
}

// ---------------------------------------------------------------------------
extern "C" void kernel_launch(void* const* d_in, const int* in_sizes, int n_in,
                              void* d_out, int out_size, void* d_ws, size_t ws_size,
                              hipStream_t stream) {
    const float* X      = (const float*)d_in[0];
    const float* mask   = (const float*)d_in[1];
    const int*   resi   = (const int*)  d_in[2];
    const float* W_pos  = (const float*)d_in[3];
    const float* b_pos  = (const float*)d_in[4];
    const float* W_edge = (const float*)d_in[5];
    const float* gamma  = (const float*)d_in[6];
    const float* beta   = (const float*)d_in[7];
    float* out = (float*)d_out;

    float* atoms = (float*)d_ws;                                     // 491520 B
    int*   E_idx = (int*)((char*)d_ws + (size_t)NRES * 15 * 4);      // 983040 B
    half8* Wfh   = (half8*)((char*)d_ws + 1474560);                  // 106496 B
    half8* Wfl   = (half8*)((char*)d_ws + 1581056);                  // 106496 B
    float* caTx  = (float*)((char*)d_ws + 1687552);                  //  32768 B
    float* caTy  = (float*)((char*)d_ws + 1720320);                  //  32768 B
    float* caTz  = (float*)((char*)d_ws + 1753088);                  //  32768 B

    atoms_kernel<<<(NRES + 255) / 256, 256, 0, stream>>>(X, atoms, caTx, caTy, caTz);
    wprep_kernel<<<(KT * 8 * 64 + 255) / 256, 256, 0, stream>>>(W_edge, Wfh, Wfl);
    topk_kernel<<<NRES / 8, 256, 0, stream>>>(caTx, caTy, caTz, mask, E_idx);
    edge_kernel<<<NEDGE / ME, 256, 0, stream>>>(atoms, E_idx, resi,
                                                W_pos, b_pos, Wfh, Wfl, gamma, beta, out);
}

// Round 11
// 285.360 us; speedup vs baseline: 1.0930x; 1.0930x over previous
//
#include <hip/hip_runtime.h>
#include <hip/hip_bf16.h>
#include <math.h>

// Problem constants (fixed by setup_inputs: B=4, L=2048)
#define BB      4
#define LL      2048
#define KNB     30
#define NRES    (BB*LL)          // 8192
#define NEDGE   (NRES*KNB)       // 245760
#define EDGE_IN 416              // 16 pos + 25*16 RBF = 13 * 32
#define KT      13               // K-tiles of 32
#define KTA     7                // pass-A k-tiles (features 0..223)
#define ME      64               // edges per block in edge kernel
#define AST2    232              // A-tile row stride in fp16 for 7-tile buffer (464 B, 16B-aligned)
#define FINF    3.4e38f
#define LOG2E   1.44269504088896340736f

typedef __attribute__((ext_vector_type(8))) _Float16 half8;
typedef __attribute__((ext_vector_type(4))) float floatx4;

__device__ __constant__ int d_PA[25] = {0,1,2,3,4,0,0,0,0,1,1,1,4,4,3,1,2,3,4,2,3,4,2,3,2};
__device__ __constant__ int d_PB[25] = {0,1,2,3,4,1,2,3,4,2,3,4,2,3,2,0,0,0,0,1,1,1,4,4,3};

__device__ __forceinline__ unsigned short f2h_bits(float x) {
    _Float16 h = (_Float16)x;
    union { _Float16 h; unsigned short u; } v; v.h = h;
    return v.u;
}
__device__ __forceinline__ unsigned pack2h(float a, float b) {
    return (unsigned)f2h_bits(a) | ((unsigned)f2h_bits(b) << 16);
}

// ---------------------------------------------------------------------------
// Kernel 1: per-residue atom construction.  atoms[r][5][3] = [Ca,N,C,O,Cb].
// Also emits the Ca SoA transpose (caTx/y/z) for coalesced topk loads.
// ---------------------------------------------------------------------------
__global__ __launch_bounds__(256) void atoms_kernel(const float* __restrict__ X,
                                                    float* __restrict__ atoms,
                                                    float* __restrict__ caTx,
                                                    float* __restrict__ caTy,
                                                    float* __restrict__ caTz) {
    int r = blockIdx.x * blockDim.x + threadIdx.x;
    if (r >= NRES) return;
    const float* xr = X + (size_t)r * 12;
    float Nx = xr[0],  Ny = xr[1],  Nz = xr[2];
    float Ax = xr[3],  Ay = xr[4],  Az = xr[5];   // Ca
    float Cx = xr[6],  Cy = xr[7],  Cz = xr[8];
    float Ox = xr[9],  Oy = xr[10], Oz = xr[11];
    float bx = Ax - Nx, by = Ay - Ny, bz = Az - Nz;
    float cx = Cx - Ax, cy = Cy - Ay, cz = Cz - Az;
    float ax = by * cz - bz * cy;
    float ay = bz * cx - bx * cz;
    float az = bx * cy - by * cx;
    float Cbx = -0.58273431f * ax + 0.56802827f * bx - 0.54067466f * cx + Ax;
    float Cby = -0.58273431f * ay + 0.56802827f * by - 0.54067466f * cy + Ay;
    float Cbz = -0.58273431f * az + 0.56802827f * bz - 0.54067466f * cz + Az;
    float* o = atoms + (size_t)r * 15;
    o[0]  = Ax;  o[1]  = Ay;  o[2]  = Az;
    o[3]  = Nx;  o[4]  = Ny;  o[5]  = Nz;
    o[6]  = Cx;  o[7]  = Cy;  o[8]  = Cz;
    o[9]  = Ox;  o[10] = Oy;  o[11] = Oz;
    o[12] = Cbx; o[13] = Cby; o[14] = Cbz;
    caTx[r] = Ax; caTy[r] = Ay; caTz[r] = Az;     // exact copies of X values
}

// ---------------------------------------------------------------------------
// Kernel 2: top-K — ONE WAVE PER RESIDUE, cached-head tournament, ZERO LDS.
// (round-6 version — best measured total)
// ---------------------------------------------------------------------------
__global__ __launch_bounds__(256, 6) void topk_kernel(const float* __restrict__ caTx,
                                                      const float* __restrict__ caTy,
                                                      const float* __restrict__ caTz,
                                                      const float* __restrict__ mask,
                                                      int* __restrict__ E_idx) {
#pragma clang fp contract(off)
    int t    = threadIdx.x;
    int wid  = t >> 6;
    int lane = t & 63;
    int bi   = blockIdx.x * 4 + wid;      // residue
    int b    = bi >> 11;
    int j0   = b << 11;

    float cx = caTx[bi], cy = caTy[bi], cz = caTz[bi];
    float mi = mask[bi];

    float aa[32];
    float lmax = 0.0f;
#pragma unroll
    for (int i = 0; i < 32; i++) {
        int j = j0 + i * 64 + lane;
        float dx = cx - caTx[j], dy = cy - caTy[j], dz = cz - caTz[j];
        float ssq = ((dx * dx + dy * dy) + dz * dz) + 1e-6f;
        float m2  = mask[j] * mi;
        float Dj  = m2 * sqrtf(ssq);
        aa[i] = Dj;
        lmax = fmaxf(lmax, Dj);
    }
    for (int off = 32; off; off >>= 1) lmax = fmaxf(lmax, __shfl_xor(lmax, off));

    // adjust in place (exact no-op when mask==1) and build sorted-4 cache
    float l0 = FINF, l1 = FINF, l2 = FINF, l3 = FINF;
    int   i0 = 0,    i1 = 0,    i2 = 0,    i3 = 0;     // slot; global j = (slot<<6)|lane
#pragma unroll
    for (int i = 0; i < 32; i++) {
        float m2 = mask[j0 + i * 64 + lane] * mi;
        float v  = aa[i] + (1.0f - m2) * lmax;
        aa[i] = v;
        bool c0 = v < l0, c1 = v < l1, c2 = v < l2, c3 = v < l3;
        l3 = c2 ? l2 : (c3 ? v : l3);  i3 = c2 ? i2 : (c3 ? i : i3);
        l2 = c1 ? l1 : (c2 ? v : l2);  i2 = c1 ? i1 : (c2 ? i : i2);
        l1 = c0 ? l0 : (c1 ? v : l1);  i1 = c0 ? i0 : (c1 ? i : i1);
        l0 = c0 ? v  : l0;             i0 = c0 ? i  : i0;
    }

    unsigned consumed = 0;
    int* outp = E_idx + (size_t)bi * KNB;
#pragma unroll 1
    for (int r = 0; r < KNB; r++) {
        float bv = l0;
        int   bj = (i0 << 6) | lane;
        for (int off = 1; off < 64; off <<= 1) {
            float ov = __shfl_xor(bv, off);
            int   oj = __shfl_xor(bj, off);
            if (ov < bv || (ov == bv && oj < bj)) { bv = ov; bj = oj; }
        }
        if (lane == 0) outp[r] = bj;
        bool mine = ((bj & 63) == lane);
        if (mine) {
            consumed |= 1u << ((unsigned)bj >> 6);   // mark own slot consumed
            l0 = l1; i0 = i1;
            l1 = l2; i1 = i2;
            l2 = l3; i2 = i3;
            l3 = FINF;
        }
        bool need = mine && (l0 == FINF) && (r < KNB - 1);
        if (need) {                                  // rare: lane won a 5th time
            l0 = FINF; l1 = FINF; l2 = FINF; l3 = FINF;
            i0 = 0; i1 = 0; i2 = 0; i3 = 0;
#pragma unroll
            for (int i = 0; i < 32; i++) {
                float v = (consumed & (1u << i)) ? FINF : aa[i];
                bool c0 = v < l0, c1 = v < l1, c2 = v < l2, c3 = v < l3;
                l3 = c2 ? l2 : (c3 ? v : l3);  i3 = c2 ? i2 : (c3 ? i : i3);
                l2 = c1 ? l1 : (c2 ? v : l2);  i2 = c1 ? i1 : (c2 ? i : i2);
                l1 = c0 ? l0 : (c1 ? v : l1);  i1 = c0 ? i0 : (c1 ? i : i1);
                l0 = c0 ? v  : l0;             i0 = c0 ? i  : i0;
            }
        }
    }
}

// ---------------------------------------------------------------------------
// Kernel 2.5: pre-swizzle W_edge (fp32 [416][128]) into SPLIT fp16 B-fragment
// order: Wh = fp16(W), Wl = fp16(W - Wh).  Layout [kk][nt][lane] of half8:
// element holds W[k = kk*32 + (lane>>4)*8 + j][n = nt*16 + (lane&15)].
// ---------------------------------------------------------------------------
__global__ __launch_bounds__(256) void wprep_kernel(const float* __restrict__ W_edge,
                                                    half8* __restrict__ Wfh,
                                                    half8* __restrict__ Wfl) {
    int t = blockIdx.x * blockDim.x + threadIdx.x;
    if (t >= KT * 8 * 64) return;
    int kk   = t >> 9;
    int rem  = t & 511;
    int nt   = rem >> 6;
    int lane = rem & 63;
    int n  = nt * 16 + (lane & 15);
    int kb = kk * 32 + (lane >> 4) * 8;
    half8 vh, vl;
#pragma unroll
    for (int j = 0; j < 8; j++) {
        float w = W_edge[(size_t)(kb + j) * 128 + n];
        _Float16 wh = (_Float16)w;
        vh[j] = wh;
        vl[j] = (_Float16)(w - (float)wh);
    }
    Wfh[t] = vh;
    Wfl[t] = vl;
}

// ---------------------------------------------------------------------------
// Kernel 3: edge featurization (fp16 A-tile) + 2-term MFMA GEMM + LN.
// E = Ah*Wh + Ah*Wl = Ah*W with W exact (split fp16 W); only error is fp16
// rounding of A (~1.6e-3 post-LN, well inside tolerance).  Dropping the Al
// array removes: 1/3 of the MFMAs (24->16/kk), 21.5 KB of LDS (51.2->37.6 KB
// => 4 blocks/CU, was 3), and ~40% of the fill VALU.  2-way K time-split
// (7+6 k-tiles) over a single Ah buffer, ME=64, acc[2][4] per wave.
// ---------------------------------------------------------------------------
__global__ __launch_bounds__(256) void edge_kernel(const float* __restrict__ atoms,
                                                   const int* __restrict__ E_idx,
                                                   const int* __restrict__ resi,
                                                   const float* __restrict__ W_pos,
                                                   const float* __restrict__ b_pos,
                                                   const half8* __restrict__ Wfh,
                                                   const half8* __restrict__ Wfl,
                                                   const float* __restrict__ gamma,
                                                   const float* __restrict__ beta,
                                                   float* __restrict__ out) {
    __shared__ _Float16 Ah[ME * AST2];             // 29696 B
    __shared__ float Dl[ME][26];                   //  6656 B
    __shared__ float redS[2][ME];                  //   512 B
    __shared__ int   s_gi[ME], s_gj[ME], s_d[ME];  //   768 B

    int t  = threadIdx.x;
    int e0 = blockIdx.x * ME;

    if (t < ME) {
        int e  = e0 + t;
        int gi = e / KNB;
        int k  = e - gi * KNB;
        int b  = gi >> 11;
        int j  = E_idx[(size_t)gi * KNB + k];
        s_gi[t] = gi;
        s_gj[t] = (b << 11) + j;
        int off = resi[gi] - resi[(b << 11) + j];
        int d = off + 32;
        s_d[t] = d < 0 ? 0 : (d > 64 ? 64 : d);
    }
    __syncthreads();

    for (int idx = t; idx < ME * 25; idx += 256) {
        int e = idx / 25, p = idx - e * 25;
        const float* Ar = atoms + (size_t)s_gi[e] * 15 + d_PA[p] * 3;
        const float* Br = atoms + (size_t)s_gj[e] * 15 + d_PB[p] * 3;
        float dx = Ar[0] - Br[0];
        float dy = Ar[1] - Br[1];
        float dz = Ar[2] - Br[2];
        Dl[e][p] = sqrtf(dx * dx + dy * dy + dz * dz + 1e-6f);
    }
    __syncthreads();

    int fe  = t >> 2;           // 0..63 (edge for fill)
    int fj4 = t & 3;
    const float* dle = Dl[fe];
    _Float16* fah = &Ah[fe * AST2];

    // --- fill pass A: features 0..223 (pos-emb + RBF pairs i=0..25) ---
    {
        {                          // pos-emb features c = fj4*4 .. +3
            int c = fj4 * 4;
            int dpos = s_d[fe];
            const float* wp = W_pos + dpos * 16 + c;
            float v0 = wp[0] + b_pos[c + 0];
            float v1 = wp[1] + b_pos[c + 1];
            float v2 = wp[2] + b_pos[c + 2];
            float v3 = wp[3] + b_pos[c + 3];
            *(unsigned*)&fah[c + 0] = pack2h(v0, v1);
            *(unsigned*)&fah[c + 2] = pack2h(v2, v3);
        }
        // RBF pairs: c2 = 2*(fj4 + 4i), i = 0..25 -> buffer col 16+c2 (<=222)
#pragma unroll
        for (int i = 0; i < 26; i++) {
            int c2 = 2 * (fj4 + 4 * i);
            int p  = c2 >> 4;
            int r  = c2 & 15;
            float D = dle[p];
            float mu0 = 2.0f + (float)r * (20.0f / 15.0f);
            float mu1 = 2.0f + (float)(r + 1) * (20.0f / 15.0f);
            float t0 = (D - mu0) * 0.8f;
            float t1 = (D - mu1) * 0.8f;
            float g0 = __builtin_amdgcn_exp2f(-(t0 * t0) * LOG2E);
            float g1 = __builtin_amdgcn_exp2f(-(t1 * t1) * LOG2E);
            *(unsigned*)&fah[16 + c2] = pack2h(g0, g1);
        }
    }
    __syncthreads();

    // --- MFMA GEMM: 64x416 x 416x128 -> fp32, 2-term (exact-W), 2-way K split ---
    int lane  = t & 63;
    int w     = t >> 6;
    int ms    = w & 1;             // edge strip pair: rows ms*32 .. ms*32+31
    int h     = w >> 1;            // feature half (0: n 0..63, 1: n 64..127)
    int m     = lane & 15;
    int quad  = lane >> 4;
    const _Float16* pah = &Ah[(ms * 32 + m) * AST2 + quad * 8];

    floatx4 acc[2][4];
#pragma unroll
    for (int s = 0; s < 2; s++)
#pragma unroll
        for (int c = 0; c < 4; c++) acc[s][c] = (floatx4){0.f, 0.f, 0.f, 0.f};

    half8 bh[4], bl[4], bnh[4], bnl[4];
#pragma unroll
    for (int c = 0; c < 4; c++) {
        int idx = (h * 4 + c) * 64 + lane;
        bh[c] = Wfh[idx];
        bl[c] = Wfl[idx];
    }

    // pass A: k-tiles 0..6 (prefetch kk+1 <= 7 always valid)
#pragma unroll 1
    for (int kk = 0; kk < KTA; kk++) {
        half8 a_hi0 = *(const half8*)(pah + kk * 32);
        half8 a_hi1 = *(const half8*)(pah + 16 * AST2 + kk * 32);
#pragma unroll
        for (int c = 0; c < 4; c++) {
            int idx = ((kk + 1) * 8 + h * 4 + c) * 64 + lane;
            bnh[c] = Wfh[idx];
            bnl[c] = Wfl[idx];
        }
#pragma unroll
        for (int c = 0; c < 4; c++) {
            acc[0][c] = __builtin_amdgcn_mfma_f32_16x16x32_f16(a_hi0, bh[c], acc[0][c], 0, 0, 0);
            acc[1][c] = __builtin_amdgcn_mfma_f32_16x16x32_f16(a_hi1, bh[c], acc[1][c], 0, 0, 0);
            acc[0][c] = __builtin_amdgcn_mfma_f32_16x16x32_f16(a_hi0, bl[c], acc[0][c], 0, 0, 0);
            acc[1][c] = __builtin_amdgcn_mfma_f32_16x16x32_f16(a_hi1, bl[c], acc[1][c], 0, 0, 0);
        }
#pragma unroll
        for (int c = 0; c < 4; c++) { bh[c] = bnh[c]; bl[c] = bnl[c]; }
    }

    __syncthreads();   // all waves done reading buffer before overwrite

    // --- fill pass B: features 224..415 (RBF pairs i=26..49), col = c2-208 ---
    {
#pragma unroll
        for (int i = 26; i < 50; i++) {
            int c2 = 2 * (fj4 + 4 * i);
            int p  = c2 >> 4;
            int r  = c2 & 15;
            float D = dle[p];
            float mu0 = 2.0f + (float)r * (20.0f / 15.0f);
            float mu1 = 2.0f + (float)(r + 1) * (20.0f / 15.0f);
            float t0 = (D - mu0) * 0.8f;
            float t1 = (D - mu1) * 0.8f;
            float g0 = __builtin_amdgcn_exp2f(-(t0 * t0) * LOG2E);
            float g1 = __builtin_amdgcn_exp2f(-(t1 * t1) * LOG2E);
            int col = c2 - 208;
            *(unsigned*)&fah[col] = pack2h(g0, g1);
        }
    }
    __syncthreads();

    // pass B: k-tiles 7..12 (bh holds B(7) from pass-A pipeline; guard at kk==12)
#pragma unroll 1
    for (int kk = KTA; kk < KT; kk++) {
        half8 a_hi0 = *(const half8*)(pah + (kk - KTA) * 32);
        half8 a_hi1 = *(const half8*)(pah + 16 * AST2 + (kk - KTA) * 32);
        if (kk < KT - 1) {
#pragma unroll
            for (int c = 0; c < 4; c++) {
                int idx = ((kk + 1) * 8 + h * 4 + c) * 64 + lane;
                bnh[c] = Wfh[idx];
                bnl[c] = Wfl[idx];
            }
        }
#pragma unroll
        for (int c = 0; c < 4; c++) {
            acc[0][c] = __builtin_amdgcn_mfma_f32_16x16x32_f16(a_hi0, bh[c], acc[0][c], 0, 0, 0);
            acc[1][c] = __builtin_amdgcn_mfma_f32_16x16x32_f16(a_hi1, bh[c], acc[1][c], 0, 0, 0);
            acc[0][c] = __builtin_amdgcn_mfma_f32_16x16x32_f16(a_hi0, bl[c], acc[0][c], 0, 0, 0);
            acc[1][c] = __builtin_amdgcn_mfma_f32_16x16x32_f16(a_hi1, bl[c], acc[1][c], 0, 0, 0);
        }
#pragma unroll
        for (int c = 0; c < 4; c++) { bh[c] = bnh[c]; bl[c] = bnl[c]; }
    }

    // --- LayerNorm epilogue: per edge, features split across wave pairs ---
    // D[row = quad*4 + r][col = m] per strip; edge_local = ms*32 + s*16 + quad*4 + r.
#pragma unroll
    for (int s = 0; s < 2; s++) {
        int elb = ms * 32 + s * 16 + quad * 4;
        float sarr[4];
#pragma unroll
        for (int r = 0; r < 4; r++) {
            float sm = acc[s][0][r] + acc[s][1][r] + acc[s][2][r] + acc[s][3][r];
            for (int msk = 1; msk <= 8; msk <<= 1) sm += __shfl_xor(sm, msk);
            sarr[r] = sm;
        }
        if (m == 0) {
#pragma unroll
            for (int r = 0; r < 4; r++) redS[h][elb + r] = sarr[r];
        }
        __syncthreads();
        float mu[4];
#pragma unroll
        for (int r = 0; r < 4; r++) mu[r] = (redS[0][elb + r] + redS[1][elb + r]) * (1.0f / 128.0f);
        __syncthreads();
        float dvv[4][4];
#pragma unroll
        for (int r = 0; r < 4; r++) {
            float v = 0.f;
#pragma unroll
            for (int c = 0; c < 4; c++) { dvv[c][r] = acc[s][c][r] - mu[r]; v += dvv[c][r] * dvv[c][r]; }
            for (int msk = 1; msk <= 8; msk <<= 1) v += __shfl_xor(v, msk);
            if (m == 0) redS[h][elb + r] = v;
        }
        __syncthreads();
#pragma unroll
        for (int r = 0; r < 4; r++) {
            float var  = (redS[0][elb + r] + redS[1][elb + r]) * (1.0f / 128.0f);
            float rstd = rsqrtf(var + 1e-5f);
            int e = e0 + elb + r;
            float* orow = out + (size_t)e * 128;
#pragma unroll
            for (int c = 0; c < 4; c++) {
                int n = (h * 4 + c) * 16 + m;
                orow[n] = dvv[c][r] * rstd * gamma[n] + beta[n];
            }
        }
        if (s == 0) __syncthreads();   // redS reused by strip 1
    }
}

// ---------------------------------------------------------------------------
extern "C" void kernel_launch(void* const* d_in, const int* in_sizes, int n_in,
                              void* d_out, int out_size, void* d_ws, size_t ws_size,
                              hipStream_t stream) {
    const float* X      = (const float*)d_in[0];
    const float* mask   = (const float*)d_in[1];
    const int*   resi   = (const int*)  d_in[2];
    const float* W_pos  = (const float*)d_in[3];
    const float* b_pos  = (const float*)d_in[4];
    const float* W_edge = (const float*)d_in[5];
    const float* gamma  = (const float*)d_in[6];
    const float* beta   = (const float*)d_in[7];
    float* out = (float*)d_out;

    float* atoms = (float*)d_ws;                                     // 491520 B
    int*   E_idx = (int*)((char*)d_ws + (size_t)NRES * 15 * 4);      // 983040 B
    half8* Wfh   = (half8*)((char*)d_ws + 1474560);                  // 106496 B
    half8* Wfl   = (half8*)((char*)d_ws + 1581056);                  // 106496 B
    float* caTx  = (float*)((char*)d_ws + 1687552);                  //  32768 B
    float* caTy  = (float*)((char*)d_ws + 1720320);                  //  32768 B
    float* caTz  = (float*)((char*)d_ws + 1753088);                  //  32768 B

    atoms_kernel<<<(NRES + 255) / 256, 256, 0, stream>>>(X, atoms, caTx, caTy, caTz);
    wprep_kernel<<<(KT * 8 * 64 + 255) / 256, 256, 0, stream>>>(W_edge, Wfh, Wfl);
    topk_kernel<<<NRES / 4, 256, 0, stream>>>(caTx, caTy, caTz, mask, E_idx);
    edge_kernel<<<NEDGE / ME, 256, 0, stream>>>(atoms, E_idx, resi,
                                                W_pos, b_pos, Wfh, Wfl, gamma, beta, out);
}